// Round 1
// baseline (353.372 us; speedup 1.0000x reference)
//
#include <hip/hip_runtime.h>
#include <math.h>

// Fixed-point LeNet, B=2048, one block per image, fully fused in LDS.
//
// Output layout (fp32, concatenated flat in reference return order):
//   logp[2048,10], conv1_in[2048,784], conv1_out[2048,5760],
//   conv2_in[2048,1440], conv2_out[2048,1280], fc1_in[2048,320],
//   fc1_out[2048,50], fc2_in[2048,50], fc2_out[2048,10]

#define NB 2048

#define OFF_LOGP   0
#define OFF_C1IN   (OFF_LOGP  + NB*10)
#define OFF_C1OUT  (OFF_C1IN  + NB*784)
#define OFF_C2IN   (OFF_C1OUT + NB*5760)
#define OFF_C2OUT  (OFF_C2IN  + NB*1440)
#define OFF_FC1IN  (OFF_C2OUT + NB*1280)
#define OFF_FC1OUT (OFF_FC1IN + NB*320)
#define OFF_FC2IN  (OFF_FC1OUT+ NB*50)
#define OFF_FC2OUT (OFF_FC2IN + NB*50)

__device__ __forceinline__ float clamp8(float v) {
    return fminf(fmaxf(v, -8.0f), 7.0f);
}

// quantize+clamp in the x256 scaled domain: clamp(rint(p*256), -2048, 1792)
__device__ __forceinline__ float qclamp_s(float sprod) {
    float r = rintf(sprod);
    return fminf(fmaxf(r, -2048.0f), 1792.0f);
}

__global__ __launch_bounds__(256, 4)
void net_kernel(const float* __restrict__ x,
                const float* __restrict__ cw1, const float* __restrict__ cb1,
                const float* __restrict__ cw2, const float* __restrict__ cb2,
                const float* __restrict__ fw1, const float* __restrict__ fb1,
                const float* __restrict__ fw2, const float* __restrict__ fb2,
                float* __restrict__ out)
{
    __shared__ float s_w1[250];                     // conv1 w * 256 (quantized, scaled)
    __shared__ float s_b1[10];                      // conv1 b * 256
    __shared__ float s_w2[5000];                    // conv2 w * 256
    __shared__ float s_b2[20];
    __shared__ __align__(16) float s_x[784];        // quantized input image
    __shared__ float s_c1[5760];                    // conv1 output [10][24][24]
    __shared__ __align__(16) float s_p1[1440];      // pooled+relu [10][12][12]
    __shared__ float s_c2[1280];                    // conv2 output [20][8][8]
    __shared__ float s_p2[320];                     // pooled+relu+CLAMPED (fc1 x)
    __shared__ float s_fc2in[50];                   // clamped fc2 x
    __shared__ float s_fc2out[10];

    const int t   = threadIdx.x;
    const int img = blockIdx.x;

    // ---- stage weights (quantize to 1/256 grid, keep x256 scaled) ----
    if (t < 250) s_w1[t] = rintf(cw1[t] * 256.0f);          // quant(w,8)*256
    if (t < 10)  s_b1[t] = rintf(cb1[t] * 256.0f);          // quant(b,8)*256 (no clamp in conv)
    for (int i = t; i < 5000; i += 256) s_w2[i] = rintf(cw2[i] * 256.0f);
    if (t < 20)  s_b2[t] = rintf(cb2[t] * 256.0f);

    // ---- quantize input, store conv1_input ----
    const float* xg = x + img * 784;
    float* c1in_g = out + OFF_C1IN + img * 784;
    for (int i = t; i < 784; i += 256) {
        float v = rintf(xg[i] * 256.0f) * (1.0f / 256.0f);
        s_x[i] = v;
        c1in_g[i] = v;
    }
    __syncthreads();

    // ---- conv1: 10x24x24; task = (co,i) row, 24 outputs/thread, 240 threads ----
    if (t < 240) {
        const int co = t / 24, i = t % 24;
        float acc[24];
        #pragma unroll
        for (int j = 0; j < 24; j++) acc[j] = 0.0f;

        #pragma unroll
        for (int p = 0; p < 5; p++) {
            float xr[28];
            const float* row = &s_x[(i + p) * 28];
            #pragma unroll
            for (int k = 0; k < 7; k++) {
                float4 v4 = *(const float4*)(row + 4 * k);
                xr[4*k] = v4.x; xr[4*k+1] = v4.y; xr[4*k+2] = v4.z; xr[4*k+3] = v4.w;
            }
            #pragma unroll
            for (int q = 0; q < 5; q++) {
                float w = s_w1[co * 25 + p * 5 + q];
                #pragma unroll
                for (int j = 0; j < 24; j++) {
                    acc[j] += qclamp_s(xr[q + j] * w);
                }
            }
        }
        const float b = s_b1[co];
        float* gdst = out + OFF_C1OUT + img * 5760 + co * 576 + i * 24;
        float* sdst = &s_c1[co * 576 + i * 24];
        #pragma unroll
        for (int j = 0; j < 24; j++) {
            float v = (acc[j] + b) * (1.0f / 256.0f);   // exact; quant is a no-op
            sdst[j] = v;
            gdst[j] = v;
        }
    }
    __syncthreads();

    // ---- pool1 + relu -> conv2_input [10][12][12] ----
    {
        float* g = out + OFF_C2IN + img * 1440;
        for (int o = t; o < 1440; o += 256) {
            int co = o / 144, r = o % 144, i = r / 12, j = r % 12;
            const float* b0 = &s_c1[co * 576 + (2 * i) * 24 + 2 * j];
            float m = fmaxf(fmaxf(b0[0], b0[1]), fmaxf(b0[24], b0[25]));
            m = fmaxf(m, 0.0f);                         // relu; quant no-op (grid)
            s_p1[o] = m;
            g[o] = m;
        }
    }
    __syncthreads();

    // ---- conv2: 20x8x8; task = (co,i) row, 8 outputs/thread, 160 threads ----
    if (t < 160) {
        const int co = t / 8, i = t % 8;
        float acc[8];
        #pragma unroll
        for (int j = 0; j < 8; j++) acc[j] = 0.0f;

        for (int ci = 0; ci < 10; ci++) {
            #pragma unroll
            for (int p = 0; p < 5; p++) {
                float xr[12];
                const float* row = &s_p1[ci * 144 + (i + p) * 12];
                #pragma unroll
                for (int k = 0; k < 3; k++) {
                    float4 v4 = *(const float4*)(row + 4 * k);
                    xr[4*k] = v4.x; xr[4*k+1] = v4.y; xr[4*k+2] = v4.z; xr[4*k+3] = v4.w;
                }
                #pragma unroll
                for (int q = 0; q < 5; q++) {
                    float w = s_w2[((co * 10 + ci) * 5 + p) * 5 + q];
                    #pragma unroll
                    for (int j = 0; j < 8; j++) {
                        acc[j] += qclamp_s(xr[q + j] * w);
                    }
                }
            }
        }
        const float b = s_b2[co];
        float* gdst = out + OFF_C2OUT + img * 1280 + co * 64 + i * 8;
        float* sdst = &s_c2[co * 64 + i * 8];
        #pragma unroll
        for (int j = 0; j < 8; j++) {
            float v = (acc[j] + b) * (1.0f / 256.0f);
            sdst[j] = v;
            gdst[j] = v;
        }
    }
    __syncthreads();

    // ---- pool2 + relu -> fc1_input [320] (store raw; keep clamped in LDS) ----
    {
        float* g = out + OFF_FC1IN + img * 320;
        for (int o = t; o < 320; o += 256) {
            int co = o / 16, r = o % 16, i = r / 4, j = r % 4;
            const float* b0 = &s_c2[co * 64 + (2 * i) * 8 + 2 * j];
            float m = fmaxf(fmaxf(b0[0], b0[1]), fmaxf(b0[8], b0[9]));
            m = fmaxf(m, 0.0f);
            g[o] = m;                                   // fc1_input (pre-clamp)
            s_p2[o] = clamp8(m);                        // round_max(quant(x)) for fc
        }
    }
    __syncthreads();

    // ---- fc1: 50 outputs ----
    if (t < 50) {
        const int j = t;
        const float* wrow = fw1 + j * 320;
        float acc = clamp8(rintf(fb1[j] * 256.0f) * (1.0f / 256.0f));  // round_max(quant(b))
        for (int i = 0; i < 320; i++) {
            float wq = clamp8(rintf(wrow[i] * 256.0f) * (1.0f / 256.0f));
            acc = fmaf(s_p2[i], wq, acc);
        }
        float o1 = rintf(clamp8(acc) * 256.0f) * (1.0f / 256.0f);      // quant(round_max(out))
        out[OFF_FC1OUT + img * 50 + j] = o1;            // fc1_output
        float r = fmaxf(o1, 0.0f);                      // relu; quant no-op
        out[OFF_FC2IN + img * 50 + j] = r;              // fc2_input
        s_fc2in[j] = clamp8(r);
    }
    __syncthreads();

    // ---- fc2: 10 outputs ----
    if (t < 10) {
        const int j = t;
        const float* wrow = fw2 + j * 50;
        float acc = clamp8(rintf(fb2[j] * 256.0f) * (1.0f / 256.0f));
        for (int i = 0; i < 50; i++) {
            float wq = clamp8(rintf(wrow[i] * 256.0f) * (1.0f / 256.0f));
            acc = fmaf(s_fc2in[i], wq, acc);
        }
        float o2 = rintf(clamp8(acc) * 256.0f) * (1.0f / 256.0f);
        out[OFF_FC2OUT + img * 10 + j] = o2;
        s_fc2out[j] = o2;
    }
    __syncthreads();

    // ---- log_softmax over 10 classes ----
    if (t == 0) {
        float m = -1e30f;
        for (int i = 0; i < 10; i++) m = fmaxf(m, s_fc2out[i]);
        float s = 0.0f;
        for (int i = 0; i < 10; i++) s += expf(s_fc2out[i] - m);
        float lse = m + logf(s);
        for (int i = 0; i < 10; i++)
            out[OFF_LOGP + img * 10 + i] = s_fc2out[i] - lse;
    }
}

extern "C" void kernel_launch(void* const* d_in, const int* in_sizes, int n_in,
                              void* d_out, int out_size, void* d_ws, size_t ws_size,
                              hipStream_t stream) {
    const float* x   = (const float*)d_in[0];
    const float* cw1 = (const float*)d_in[1];
    const float* cb1 = (const float*)d_in[2];
    const float* cw2 = (const float*)d_in[3];
    const float* cb2 = (const float*)d_in[4];
    const float* fw1 = (const float*)d_in[5];
    const float* fb1 = (const float*)d_in[6];
    const float* fw2 = (const float*)d_in[7];
    const float* fb2 = (const float*)d_in[8];
    float* o = (float*)d_out;

    net_kernel<<<NB, 256, 0, stream>>>(x, cw1, cb1, cw2, cb2, fw1, fb1, fw2, fb2, o);
}